// Round 6
// baseline (33.337 us; speedup 1.0000x reference)
//
#include <hip/hip_runtime.h>

#define S 256
#define NF 4096
#define TILE 16
#define NT 1024            // 4 slices x 256 pixels
#define SLICES 4
#define CAPC 512           // candidate slots (avg ~40 used; overflow -> exact fallback)
#define NEARF 0.1f
#define FARF 100.0f
#define EPSF 1e-8f

// One block per 16x16 tile, 1024 threads, 2 barriers.
// Cull: 4 faces/thread, batched float4 loads, all-fp32 conservative tests
// (fp32 area error <1.5e-6 << 1e-4 margin). Survivors -> LDS: 3x float4 verts
// + 1x float4 raw bbox.
// Render: per candidate, all lanes of a wave first test the candidate bbox
// against the wave's 16x4-pixel strip (uniform predicate -> execz skip of the
// whole body). Survivors get the bit-exact __f*_rn reference math. Merge via
// (depth_bits<<32|face) min-key: order-independent, exact lowest-index
// tie-break, so atomic compaction order is irrelevant.
__global__ __launch_bounds__(NT, 4) void raster_tile(const float* __restrict__ faces,
                                                     int* __restrict__ out) {
    __shared__ float4 s_cand[CAPC][4];          // 32 KB
    __shared__ unsigned long long s_key[NT];    // 8 KB
    __shared__ int s_cnt;

    const int tile = blockIdx.x;
    const int tx0 = (tile & (S / TILE - 1)) * TILE;
    const int ty0 = (tile / (S / TILE)) * TILE;

    const int pix = threadIdx.x & 255;
    const int slice = threadIdx.x >> 8;          // wave-uniform
    const int px = tx0 + (pix & (TILE - 1));
    const int py = ty0 + (pix / TILE);
    // (2i+1-256)/256: odd numerator / pow2 -> exact in fp32.
    const float xp = (2.0f * px + 1.0f - 256.0f) * (1.0f / 256.0f);
    const float yp = (2.0f * py + 1.0f - 256.0f) * (1.0f / 256.0f);

    // Tile pixel-center bounds with margin vs ulp-level boundary flips.
    const float cxlo = (2.0f * tx0 + 1.0f - 256.0f) * (1.0f / 256.0f) - 1e-5f;
    const float cxhi = (2.0f * (tx0 + TILE - 1) + 1.0f - 256.0f) * (1.0f / 256.0f) + 1e-5f;
    const float cylo = (2.0f * ty0 + 1.0f - 256.0f) * (1.0f / 256.0f) - 1e-5f;
    const float cyhi = (2.0f * (ty0 + TILE - 1) + 1.0f - 256.0f) * (1.0f / 256.0f) + 1e-5f;

    // Wave pixel-strip bounds: lanes of a wave cover a 16x4 strip of the tile.
    const int wrow0 = ty0 + ((pix >> 6) << 2);   // wave-uniform: pix/64 * 4 rows
    const float wylo = (2.0f * wrow0 + 1.0f - 256.0f) * (1.0f / 256.0f) - 1e-5f;
    const float wyhi = (2.0f * (wrow0 + 3) + 1.0f - 256.0f) * (1.0f / 256.0f) + 1e-5f;

    // ---- cull: 4 faces/thread, all loads issued before any use ----
    float4 A[4], B[4];
    float Cz[4];
#pragma unroll
    for (int i = 0; i < 4; ++i) {
        const float* p = faces + (size_t)(i * NT + threadIdx.x) * 9;
        A[i] = *(const float4*)p;        // x0,y0,z0,x1
        B[i] = *(const float4*)(p + 4);  // y1,z1,x2,y2
        Cz[i] = p[8];                    // z2
    }
    if (threadIdx.x == 0) s_cnt = 0;
    __syncthreads();   // sits under the global-load latency

#pragma unroll
    for (int i = 0; i < 4; ++i) {
        const float x0 = A[i].x, y0 = A[i].y, x1 = A[i].w;
        const float y1 = B[i].x, x2 = B[i].z, y2 = B[i].w;
        const float bxmin = fminf(x0, fminf(x1, x2));
        const float bxmax = fmaxf(x0, fmaxf(x1, x2));
        const float bymin = fminf(y0, fminf(y1, y2));
        const float bymax = fmaxf(y0, fmaxf(y1, y2));
        bool hit = (bxmax >= cxlo) && (bxmin <= cxhi) &&
                   (bymax >= cylo) && (bymin <= cyhi);
        if (hit) {
            // 2*signed area, fp32: |err| < 1.5e-6 << 1e-4 margin, and the
            // reference's per-pixel fp32 w_sum wanders <~1e-6 from the exact
            // area, so culling area <= -1e-4 cannot lose any w_sum>0 pixel.
            const float a2 = __fsub_rn(
                __fmul_rn(__fsub_rn(x1, x0), __fsub_rn(y2, y0)),
                __fmul_rn(__fsub_rn(x2, x0), __fsub_rn(y1, y0)));
            hit = (a2 > -1e-4f);
        }
        if (hit) {
            const int slot = atomicAdd(&s_cnt, 1);
            if (slot < CAPC) {
                s_cand[slot][0] = A[i];
                s_cand[slot][1] = B[i];
                s_cand[slot][2] =
                    make_float4(Cz[i], __int_as_float(i * NT + (int)threadIdx.x), 0.0f, 0.0f);
                s_cand[slot][3] = make_float4(bxmin, bxmax, bymin, bymax);
            }
        }
    }
    __syncthreads();

    float bestd = FARF;
    int bestf = 0x7fffffff;

#define BODY(X0, Y0, Z0, X1, Y1, Z1, X2, Y2, Z2, FIDX)                                   \
    {                                                                                    \
        const float w0 = __fsub_rn(__fmul_rn(__fsub_rn(yp, Y1), __fsub_rn(X2, X1)),      \
                                   __fmul_rn(__fsub_rn(xp, X1), __fsub_rn(Y2, Y1)));     \
        const float w1 = __fsub_rn(__fmul_rn(__fsub_rn(yp, Y2), __fsub_rn(X0, X2)),      \
                                   __fmul_rn(__fsub_rn(xp, X2), __fsub_rn(Y0, Y2)));     \
        const float w2 = __fsub_rn(__fmul_rn(__fsub_rn(yp, Y0), __fsub_rn(X1, X0)),      \
                                   __fmul_rn(__fsub_rn(xp, X0), __fsub_rn(Y1, Y0)));     \
        const bool inside = (__fmul_rn(w0, w1) > 0.0f) && (__fmul_rn(w1, w2) > 0.0f);    \
        const float wsum = __fadd_rn(__fadd_rn(w0, w1), w2);                             \
        if (inside && (wsum > 0.0f)) {                                                   \
            float denom = __fadd_rn(__fadd_rn(__fdiv_rn(w0, Z0), __fdiv_rn(w1, Z1)),     \
                                    __fdiv_rn(w2, Z2));                                  \
            denom = (fabsf(denom) > EPSF) ? denom : EPSF;                                \
            const float zp = __fdiv_rn(wsum, denom);                                     \
            if ((zp > NEARF) && (zp < FARF)) {                                           \
                if (zp < bestd || (zp == bestd && (FIDX) < bestf)) {                     \
                    bestd = zp;                                                          \
                    bestf = (FIDX);                                                     \
                }                                                                        \
            }                                                                            \
        }                                                                                \
    }

    const int n = s_cnt;
    if (n <= CAPC) {
        // ---- render: sliced scan; wave-level bbox early-out per candidate ----
        for (int i = slice; i < n; i += SLICES) {
            const float4 bb = s_cand[i][3];      // broadcast read
            // Uniform across the wave (same LDS data, wave-uniform strip bounds
            // except cx* which are block-uniform) -> execz skip when no overlap.
            if ((bb.y >= cxlo) && (bb.x <= cxhi) && (bb.w >= wylo) && (bb.z <= wyhi)) {
                const float4 a = s_cand[i][0];
                const float4 b = s_cand[i][1];
                const float4 c = s_cand[i][2];
                BODY(a.x, a.y, a.z, a.w, b.x, b.y, b.z, b.w, c.x, __float_as_int(c.y))
            }
        }
    } else {
        // Overflow (never expected): test every face directly from global.
        for (int i = slice; i < NF; i += SLICES) {
            const float* p = faces + (size_t)i * 9;
            BODY(p[0], p[1], p[2], p[3], p[4], p[5], p[6], p[7], p[8], i)
        }
    }
#undef BODY

    // ---- merge 4 slices per pixel via packed min-key ----
    s_key[threadIdx.x] =
        ((unsigned long long)__float_as_uint(bestd) << 32) | (unsigned int)bestf;
    __syncthreads();
    if (threadIdx.x < 256) {
        unsigned long long k = s_key[threadIdx.x];
        const unsigned long long k1 = s_key[threadIdx.x + 256];
        const unsigned long long k2 = s_key[threadIdx.x + 512];
        const unsigned long long k3 = s_key[threadIdx.x + 768];
        k = k1 < k ? k1 : k;
        k = k2 < k ? k2 : k;
        k = k3 < k ? k3 : k;
        const float d = __uint_as_float((unsigned int)(k >> 32));
        const int fi = (int)(unsigned int)k;
        const int opx = tx0 + (threadIdx.x & (TILE - 1));
        const int opy = ty0 + (threadIdx.x / TILE);
        out[opy * S + opx] = (d < FARF) ? fi : -1;
    }
}

extern "C" void kernel_launch(void* const* d_in, const int* in_sizes, int n_in,
                              void* d_out, int out_size, void* d_ws, size_t ws_size,
                              hipStream_t stream) {
    const float* faces = (const float*)d_in[0];
    int* out = (int*)d_out;
    hipLaunchKernelGGL(raster_tile, dim3((S / TILE) * (S / TILE)), dim3(NT), 0, stream,
                       faces, out);
}

// Round 7
// 30.406 us; speedup vs baseline: 1.0964x; 1.0964x over previous
//
#include <hip/hip_runtime.h>

#define S 256
#define NF 4096
#define TILE 16
#define NT 1024            // 4 slices x 256 pixels
#define SLICES 4
#define CAPC 512           // candidate slots (avg ~40 used; overflow -> exact fallback)
#define NEARF 0.1f
#define FARF 100.0f
#define EPSF 1e-8f

// One block per 16x16 tile, 1024 threads, 2 barriers.
// Cull: 4 faces/thread, batched float4 loads, fp32 conservative tests (area
// error <1.5e-6 << 1e-4 margin). Survivors -> LDS with the 6 candidate-uniform
// edge deltas precomputed (same __fsub_rn ops the reference does per pixel ->
// bit-identical values, computed once instead of per body).
// Render: simple sliced scan (best-measured shape), bit-exact __f*_rn body.
// Merge via (depth_bits<<32|face) min-key: order-independent, exact
// lowest-index tie-break -> atomic compaction order is irrelevant.
// NOTE: intra-tile bbox culling is provably useless here (triangles ~19px ~
// tile size), so no early-outs.
__global__ __launch_bounds__(NT, 4) void raster_tile(const float* __restrict__ faces,
                                                     int* __restrict__ out) {
    __shared__ float4 s_cand[CAPC][4];          // 32 KB
    __shared__ unsigned long long s_key[NT];    // 8 KB
    __shared__ int s_cnt;

    const int tile = blockIdx.x;
    const int tx0 = (tile & (S / TILE - 1)) * TILE;
    const int ty0 = (tile / (S / TILE)) * TILE;

    const int pix = threadIdx.x & 255;
    const int slice = threadIdx.x >> 8;          // wave-uniform
    const int px = tx0 + (pix & (TILE - 1));
    const int py = ty0 + (pix / TILE);
    // (2i+1-256)/256: odd numerator / pow2 -> exact in fp32.
    const float xp = (2.0f * px + 1.0f - 256.0f) * (1.0f / 256.0f);
    const float yp = (2.0f * py + 1.0f - 256.0f) * (1.0f / 256.0f);

    // Tile pixel-center bounds with margin vs ulp-level boundary flips.
    const float cxlo = (2.0f * tx0 + 1.0f - 256.0f) * (1.0f / 256.0f) - 1e-5f;
    const float cxhi = (2.0f * (tx0 + TILE - 1) + 1.0f - 256.0f) * (1.0f / 256.0f) + 1e-5f;
    const float cylo = (2.0f * ty0 + 1.0f - 256.0f) * (1.0f / 256.0f) - 1e-5f;
    const float cyhi = (2.0f * (ty0 + TILE - 1) + 1.0f - 256.0f) * (1.0f / 256.0f) + 1e-5f;

    // ---- cull: 4 faces/thread, all loads issued before any use ----
    float4 A[4], B[4];
    float Cz[4];
#pragma unroll
    for (int i = 0; i < 4; ++i) {
        const float* p = faces + (size_t)(i * NT + threadIdx.x) * 9;
        A[i] = *(const float4*)p;        // x0,y0,z0,x1
        B[i] = *(const float4*)(p + 4);  // y1,z1,x2,y2
        Cz[i] = p[8];                    // z2
    }
    if (threadIdx.x == 0) s_cnt = 0;
    __syncthreads();   // sits under the global-load latency

#pragma unroll
    for (int i = 0; i < 4; ++i) {
        const float x0 = A[i].x, y0 = A[i].y, x1 = A[i].w;
        const float y1 = B[i].x, x2 = B[i].z, y2 = B[i].w;
        const float bxmin = fminf(x0, fminf(x1, x2));
        const float bxmax = fmaxf(x0, fmaxf(x1, x2));
        const float bymin = fminf(y0, fminf(y1, y2));
        const float bymax = fmaxf(y0, fmaxf(y1, y2));
        bool hit = (bxmax >= cxlo) && (bxmin <= cxhi) &&
                   (bymax >= cylo) && (bymin <= cyhi);
        // Edge deltas: identical __fsub_rn ops to the reference's per-pixel
        // (x2-x1) etc. -> bit-identical, hoisted out of the render loop.
        const float dx21 = __fsub_rn(x2, x1), dy21 = __fsub_rn(y2, y1);
        const float dx02 = __fsub_rn(x0, x2), dy02 = __fsub_rn(y0, y2);
        const float dx10 = __fsub_rn(x1, x0), dy10 = __fsub_rn(y1, y0);
        if (hit) {
            // 2*signed area fp32: |err| < 1.5e-6 << 1e-4 margin, so no pixel
            // whose fp32 w_sum>0 can be lost to this cull.
            const float a2 = __fsub_rn(__fmul_rn(dx10, dy02 * -1.0f),
                                       __fmul_rn(dx02 * -1.0f, dy10));
            // a2 = (x1-x0)*(y2-y0) - (x2-x0)*(y1-y0); signs folded:
            // dy02*-1 = y2-y0 up to sign of __fsub_rn: -(y0-y2) == y2-y0 exactly.
            hit = (a2 > -1e-4f);
        }
        if (hit) {
            const int slot = atomicAdd(&s_cnt, 1);
            if (slot < CAPC) {
                s_cand[slot][0] = A[i];
                s_cand[slot][1] = B[i];
                s_cand[slot][2] = make_float4(
                    Cz[i], __int_as_float(i * NT + (int)threadIdx.x), dx21, dy21);
                s_cand[slot][3] = make_float4(dx02, dy02, dx10, dy10);
            }
        }
    }
    __syncthreads();

    float bestd = FARF;
    int bestf = 0x7fffffff;

    const int n = s_cnt;
    if (n <= CAPC) {
        // ---- render: sliced scan, deltas precomputed ----
        for (int i = slice; i < n; i += SLICES) {
            const float4 a = s_cand[i][0];   // broadcast reads, conflict-free
            const float4 b = s_cand[i][1];
            const float4 c = s_cand[i][2];
            const float4 d = s_cand[i][3];
            const float X0 = a.x, Y0 = a.y, Z0 = a.z, X1 = a.w;
            const float Y1 = b.x, Z1 = b.y, X2 = b.z, Y2 = b.w;
            const float Z2 = c.x;
            const int f = __float_as_int(c.y);
            const float w0 = __fsub_rn(__fmul_rn(__fsub_rn(yp, Y1), c.z),
                                       __fmul_rn(__fsub_rn(xp, X1), c.w));
            const float w1 = __fsub_rn(__fmul_rn(__fsub_rn(yp, Y2), d.x),
                                       __fmul_rn(__fsub_rn(xp, X2), d.y));
            const float w2 = __fsub_rn(__fmul_rn(__fsub_rn(yp, Y0), d.z),
                                       __fmul_rn(__fsub_rn(xp, X0), d.w));
            const bool inside = (__fmul_rn(w0, w1) > 0.0f) && (__fmul_rn(w1, w2) > 0.0f);
            const float wsum = __fadd_rn(__fadd_rn(w0, w1), w2);
            if (inside && (wsum > 0.0f)) {
                float denom = __fadd_rn(__fadd_rn(__fdiv_rn(w0, Z0), __fdiv_rn(w1, Z1)),
                                        __fdiv_rn(w2, Z2));
                denom = (fabsf(denom) > EPSF) ? denom : EPSF;
                const float zp = __fdiv_rn(wsum, denom);
                if ((zp > NEARF) && (zp < FARF)) {
                    if (zp < bestd || (zp == bestd && f < bestf)) {
                        bestd = zp;
                        bestf = f;
                    }
                }
            }
        }
    } else {
        // Overflow (never expected): test every face directly from global.
        // Conservative-cull equivalence keeps this exact.
        for (int i = slice; i < NF; i += SLICES) {
            const float* p = faces + (size_t)i * 9;
            const float X0 = p[0], Y0 = p[1], Z0 = p[2];
            const float X1 = p[3], Y1 = p[4], Z1 = p[5];
            const float X2 = p[6], Y2 = p[7], Z2 = p[8];
            const float w0 = __fsub_rn(__fmul_rn(__fsub_rn(yp, Y1), __fsub_rn(X2, X1)),
                                       __fmul_rn(__fsub_rn(xp, X1), __fsub_rn(Y2, Y1)));
            const float w1 = __fsub_rn(__fmul_rn(__fsub_rn(yp, Y2), __fsub_rn(X0, X2)),
                                       __fmul_rn(__fsub_rn(xp, X2), __fsub_rn(Y0, Y2)));
            const float w2 = __fsub_rn(__fmul_rn(__fsub_rn(yp, Y0), __fsub_rn(X1, X0)),
                                       __fmul_rn(__fsub_rn(xp, X0), __fsub_rn(Y1, Y0)));
            const bool inside = (__fmul_rn(w0, w1) > 0.0f) && (__fmul_rn(w1, w2) > 0.0f);
            const float wsum = __fadd_rn(__fadd_rn(w0, w1), w2);
            if (inside && (wsum > 0.0f)) {
                float denom = __fadd_rn(__fadd_rn(__fdiv_rn(w0, Z0), __fdiv_rn(w1, Z1)),
                                        __fdiv_rn(w2, Z2));
                denom = (fabsf(denom) > EPSF) ? denom : EPSF;
                const float zp = __fdiv_rn(wsum, denom);
                if ((zp > NEARF) && (zp < FARF)) {
                    if (zp < bestd || (zp == bestd && i < bestf)) {
                        bestd = zp;
                        bestf = i;
                    }
                }
            }
        }
    }

    // ---- merge 4 slices per pixel via packed min-key ----
    s_key[threadIdx.x] =
        ((unsigned long long)__float_as_uint(bestd) << 32) | (unsigned int)bestf;
    __syncthreads();
    if (threadIdx.x < 256) {
        unsigned long long k = s_key[threadIdx.x];
        const unsigned long long k1 = s_key[threadIdx.x + 256];
        const unsigned long long k2 = s_key[threadIdx.x + 512];
        const unsigned long long k3 = s_key[threadIdx.x + 768];
        k = k1 < k ? k1 : k;
        k = k2 < k ? k2 : k;
        k = k3 < k ? k3 : k;
        const float dd = __uint_as_float((unsigned int)(k >> 32));
        const int fi = (int)(unsigned int)k;
        const int opx = tx0 + (threadIdx.x & (TILE - 1));
        const int opy = ty0 + (threadIdx.x / TILE);
        out[opy * S + opx] = (dd < FARF) ? fi : -1;
    }
}

extern "C" void kernel_launch(void* const* d_in, const int* in_sizes, int n_in,
                              void* d_out, int out_size, void* d_ws, size_t ws_size,
                              hipStream_t stream) {
    const float* faces = (const float*)d_in[0];
    int* out = (int*)d_out;
    hipLaunchKernelGGL(raster_tile, dim3((S / TILE) * (S / TILE)), dim3(NT), 0, stream,
                       faces, out);
}

// Round 8
// 25.870 us; speedup vs baseline: 1.2887x; 1.1753x over previous
//
#include <hip/hip_runtime.h>

#define S 256
#define NF 4096
#define TILE 16
#define HTILE 8            // half-tile height: block = 16 wide x 8 tall
#define NT 1024            // 8 slices x 128 pixels
#define SLICES 8
#define CAPC 512           // candidate slots (avg ~30 used; overflow -> exact fallback)
#define NEARF 0.1f
#define FARF 100.0f
#define EPSF 1e-8f

// 512 blocks: block b handles half-tile (tile = b & 255, half = b >> 8), so the
// two halves of a tile land on different CUs (worst-tile balancing) and each CU
// holds 2 independent blocks (8 waves/SIMD -> stall interleaving).
// Cull: all 4096 faces per block, 2-face register batches (fits the 64-VGPR cap
// from __launch_bounds__(1024,8)), fp32 conservative bbox+area tests against
// the HALF-tile bounds (~25% fewer candidates than full tile).
// Render: 8 slices x 128 px, precomputed edge deltas (bit-identical __fsub_rn
// hoisted), bit-exact __f*_rn body. Merge via (depth_bits<<32|face) min-key:
// order-independent, exact lowest-index tie-break.
__global__ __launch_bounds__(NT, 8) void raster_tile(const float* __restrict__ faces,
                                                     int* __restrict__ out) {
    __shared__ float4 s_cand[CAPC][4];          // 32 KB
    __shared__ unsigned long long s_key[NT];    // 8 KB
    __shared__ int s_cnt;

    const int bx = blockIdx.x;
    const int tile = bx & 255;
    const int half = bx >> 8;
    const int tx0 = (tile & (S / TILE - 1)) * TILE;
    const int ty0 = (tile / (S / TILE)) * TILE + half * HTILE;

    const int pix = threadIdx.x & 127;           // 16 x 8 pixels
    const int slice = threadIdx.x >> 7;          // wave-uniform (64 | 128)
    const int px = tx0 + (pix & (TILE - 1));
    const int py = ty0 + (pix >> 4);
    // (2i+1-256)/256: odd numerator / pow2 -> exact in fp32.
    const float xp = (2.0f * px + 1.0f - 256.0f) * (1.0f / 256.0f);
    const float yp = (2.0f * py + 1.0f - 256.0f) * (1.0f / 256.0f);

    // Half-tile pixel-center bounds with margin vs ulp-level boundary flips.
    const float cxlo = (2.0f * tx0 + 1.0f - 256.0f) * (1.0f / 256.0f) - 1e-5f;
    const float cxhi = (2.0f * (tx0 + TILE - 1) + 1.0f - 256.0f) * (1.0f / 256.0f) + 1e-5f;
    const float cylo = (2.0f * ty0 + 1.0f - 256.0f) * (1.0f / 256.0f) - 1e-5f;
    const float cyhi = (2.0f * (ty0 + HTILE - 1) + 1.0f - 256.0f) * (1.0f / 256.0f) + 1e-5f;

    if (threadIdx.x == 0) s_cnt = 0;
    __syncthreads();

    // ---- cull: 4096 faces, 2 batches of 2 faces/thread (low VGPR) ----
#pragma unroll
    for (int g = 0; g < 2; ++g) {
        float4 A[2], B[2];
        float Cz[2];
#pragma unroll
        for (int i = 0; i < 2; ++i) {
            const int f = g * 2048 + i * 1024 + (int)threadIdx.x;
            const float* p = faces + (size_t)f * 9;
            A[i] = *(const float4*)p;        // x0,y0,z0,x1
            B[i] = *(const float4*)(p + 4);  // y1,z1,x2,y2
            Cz[i] = p[8];                    // z2
        }
#pragma unroll
        for (int i = 0; i < 2; ++i) {
            const float x0 = A[i].x, y0 = A[i].y, x1 = A[i].w;
            const float y1 = B[i].x, x2 = B[i].z, y2 = B[i].w;
            const float bxmin = fminf(x0, fminf(x1, x2));
            const float bxmax = fmaxf(x0, fmaxf(x1, x2));
            const float bymin = fminf(y0, fminf(y1, y2));
            const float bymax = fmaxf(y0, fmaxf(y1, y2));
            bool hit = (bxmax >= cxlo) && (bxmin <= cxhi) &&
                       (bymax >= cylo) && (bymin <= cyhi);
            // Edge deltas: identical __fsub_rn ops to the reference's per-pixel
            // (x2-x1) etc. -> bit-identical, hoisted out of the render loop.
            const float dx21 = __fsub_rn(x2, x1), dy21 = __fsub_rn(y2, y1);
            const float dx02 = __fsub_rn(x0, x2), dy02 = __fsub_rn(y0, y2);
            const float dx10 = __fsub_rn(x1, x0), dy10 = __fsub_rn(y1, y0);
            if (hit) {
                // 2*signed area fp32: |err| < 1.5e-6 << 1e-4 margin -> no pixel
                // whose fp32 w_sum>0 can be lost to this cull.
                const float a2 = __fsub_rn(
                    __fmul_rn(__fsub_rn(x1, x0), __fsub_rn(y2, y0)),
                    __fmul_rn(__fsub_rn(x2, x0), __fsub_rn(y1, y0)));
                hit = (a2 > -1e-4f);
            }
            if (hit) {
                const int f = g * 2048 + i * 1024 + (int)threadIdx.x;
                const int slot = atomicAdd(&s_cnt, 1);
                if (slot < CAPC) {
                    s_cand[slot][0] = A[i];
                    s_cand[slot][1] = B[i];
                    s_cand[slot][2] =
                        make_float4(Cz[i], __int_as_float(f), dx21, dy21);
                    s_cand[slot][3] = make_float4(dx02, dy02, dx10, dy10);
                }
            }
        }
    }
    __syncthreads();

    float bestd = FARF;
    int bestf = 0x7fffffff;

    const int n = s_cnt;
    if (n <= CAPC) {
        // ---- render: 8-sliced scan, deltas precomputed ----
        for (int i = slice; i < n; i += SLICES) {
            const float4 a = s_cand[i][0];   // broadcast reads, conflict-free
            const float4 b = s_cand[i][1];
            const float4 c = s_cand[i][2];
            const float4 d = s_cand[i][3];
            const float X0 = a.x, Y0 = a.y, Z0 = a.z, X1 = a.w;
            const float Y1 = b.x, Z1 = b.y, X2 = b.z, Y2 = b.w;
            const float Z2 = c.x;
            const int f = __float_as_int(c.y);
            const float w0 = __fsub_rn(__fmul_rn(__fsub_rn(yp, Y1), c.z),
                                       __fmul_rn(__fsub_rn(xp, X1), c.w));
            const float w1 = __fsub_rn(__fmul_rn(__fsub_rn(yp, Y2), d.x),
                                       __fmul_rn(__fsub_rn(xp, X2), d.y));
            const float w2 = __fsub_rn(__fmul_rn(__fsub_rn(yp, Y0), d.z),
                                       __fmul_rn(__fsub_rn(xp, X0), d.w));
            const bool inside = (__fmul_rn(w0, w1) > 0.0f) && (__fmul_rn(w1, w2) > 0.0f);
            const float wsum = __fadd_rn(__fadd_rn(w0, w1), w2);
            if (inside && (wsum > 0.0f)) {
                float denom = __fadd_rn(__fadd_rn(__fdiv_rn(w0, Z0), __fdiv_rn(w1, Z1)),
                                        __fdiv_rn(w2, Z2));
                denom = (fabsf(denom) > EPSF) ? denom : EPSF;
                const float zp = __fdiv_rn(wsum, denom);
                if ((zp > NEARF) && (zp < FARF)) {
                    if (zp < bestd || (zp == bestd && f < bestf)) {
                        bestd = zp;
                        bestf = f;
                    }
                }
            }
        }
    } else {
        // Overflow (never expected): test every face directly from global.
        // Conservative-cull equivalence keeps this exact.
        for (int i = slice; i < NF; i += SLICES) {
            const float* p = faces + (size_t)i * 9;
            const float X0 = p[0], Y0 = p[1], Z0 = p[2];
            const float X1 = p[3], Y1 = p[4], Z1 = p[5];
            const float X2 = p[6], Y2 = p[7], Z2 = p[8];
            const float w0 = __fsub_rn(__fmul_rn(__fsub_rn(yp, Y1), __fsub_rn(X2, X1)),
                                       __fmul_rn(__fsub_rn(xp, X1), __fsub_rn(Y2, Y1)));
            const float w1 = __fsub_rn(__fmul_rn(__fsub_rn(yp, Y2), __fsub_rn(X0, X2)),
                                       __fmul_rn(__fsub_rn(xp, X2), __fsub_rn(Y0, Y2)));
            const float w2 = __fsub_rn(__fmul_rn(__fsub_rn(yp, Y0), __fsub_rn(X1, X0)),
                                       __fmul_rn(__fsub_rn(xp, X0), __fsub_rn(Y1, Y0)));
            const bool inside = (__fmul_rn(w0, w1) > 0.0f) && (__fmul_rn(w1, w2) > 0.0f);
            const float wsum = __fadd_rn(__fadd_rn(w0, w1), w2);
            if (inside && (wsum > 0.0f)) {
                float denom = __fadd_rn(__fadd_rn(__fdiv_rn(w0, Z0), __fdiv_rn(w1, Z1)),
                                        __fdiv_rn(w2, Z2));
                denom = (fabsf(denom) > EPSF) ? denom : EPSF;
                const float zp = __fdiv_rn(wsum, denom);
                if ((zp > NEARF) && (zp < FARF)) {
                    if (zp < bestd || (zp == bestd && i < bestf)) {
                        bestd = zp;
                        bestf = i;
                    }
                }
            }
        }
    }

    // ---- merge 8 slices per pixel via packed min-key ----
    s_key[threadIdx.x] =
        ((unsigned long long)__float_as_uint(bestd) << 32) | (unsigned int)bestf;
    __syncthreads();
    if (threadIdx.x < 128) {
        unsigned long long k = s_key[threadIdx.x];
#pragma unroll
        for (int s = 1; s < SLICES; ++s) {
            const unsigned long long ks = s_key[threadIdx.x + 128 * s];
            k = ks < k ? ks : k;
        }
        const float dd = __uint_as_float((unsigned int)(k >> 32));
        const int fi = (int)(unsigned int)k;
        const int opx = tx0 + (threadIdx.x & (TILE - 1));
        const int opy = ty0 + (threadIdx.x >> 4);
        out[opy * S + opx] = (dd < FARF) ? fi : -1;
    }
}

extern "C" void kernel_launch(void* const* d_in, const int* in_sizes, int n_in,
                              void* d_out, int out_size, void* d_ws, size_t ws_size,
                              hipStream_t stream) {
    const float* faces = (const float*)d_in[0];
    int* out = (int*)d_out;
    hipLaunchKernelGGL(raster_tile, dim3(2 * (S / TILE) * (S / TILE)), dim3(NT), 0,
                       stream, faces, out);
}